// Round 1
// baseline (20092.213 us; speedup 1.0000x reference)
//
#include <hip/hip_runtime.h>
#include <cstdint>
#include <cstddef>

// SingleLayerLSTM: B=128, T=2048, D=64, H=256, O=32.
// Design: persistent pair-split kernel.
//  - 256 blocks x 512 threads; block = (batch p = blk&127, half q = blk>>7).
//  - Thread owns one weight column (channel c = tid>>2 within half, gate g = tid&3),
//    all 320 rows ([u;h]) as fp16 pairs in 160 VGPRs -> v_dot2_f32_f16, fp32 accum.
//  - [u_t | h_{t-1}] lives in LDS (fp16, parity double-buffered); matvec reads are
//    wave-uniform broadcast ds_read_b128.
//  - 4-lane shfl_xor combines gates; c-state replicated x4 in regs.
//  - Halves exchange h via parity-double-buffered L2 buffer + release/acquire
//    agent-scope flag (monotonic step; 0xAA poison is negative -> no init needed).
//  - y_{t-1} computed one step behind by q==0 blocks (16x32 partials + LDS reduce).

#define HH 256
#define DD 64
#define TT 2048
#define BB 128
#define OO 32
#define KR 320   // D + H rows
#define NP 160   // KR/2 fp16 pairs per column

typedef _Float16 f16x2 __attribute__((ext_vector_type(2)));

__device__ __forceinline__ f16x2 b2h(int v) { return __builtin_bit_cast(f16x2, v); }

#if __has_builtin(__builtin_amdgcn_fdot2)
__device__ __forceinline__ float fdot2(f16x2 a, f16x2 b, float c) {
  return __builtin_amdgcn_fdot2(a, b, c, false);
}
#else
__device__ __forceinline__ float fdot2(f16x2 a, f16x2 b, float c) {
  return fmaf((float)a.y, (float)b.y, fmaf((float)a.x, (float)b.x, c));
}
#endif

#if __has_builtin(__builtin_amdgcn_rcpf)
__device__ __forceinline__ float frcp(float x) { return __builtin_amdgcn_rcpf(x); }
#else
__device__ __forceinline__ float frcp(float x) { return 1.0f / x; }
#endif

// act = c + a * rcp(1 + exp2(b*x)):  sigmoid: a=1,b=-log2e... we use expf directly.
__device__ __forceinline__ float sigm(float x)  { return frcp(1.0f + __expf(-x)); }
__device__ __forceinline__ float tanhf_(float x){ return 1.0f - 2.0f * frcp(1.0f + __expf(2.0f * x)); }

__global__ __launch_bounds__(512, 2)
void lstm_persist(const float* __restrict__ u,    const float* __restrict__ x0,
                  const float* __restrict__ kfiz, const float* __restrict__ bfiz,
                  const float* __restrict__ kr,   const float* __restrict__ br,
                  const float* __restrict__ wout, const float* __restrict__ bout,
                  float* __restrict__ out, float* __restrict__ xbuf, int* __restrict__ flags)
{
  const int tid = threadIdx.x;
  const int p   = blockIdx.x & (BB - 1);   // batch item
  const int q   = blockIdx.x >> 7;         // half 0/1 (pair (b, b+128) -> same XCD under %8)
  const int c   = tid >> 2;                // channel within half [0,128)
  const int g   = tid & 3;                 // 0=f,1=i,2=z,3=r
  const int cg  = (q << 7) + c;            // global channel [0,256)

  __shared__ __align__(16) _Float16 uh[2][KR];   // [parity][ u(64) | h(256) ]
  __shared__ float yred[2][OO][17];              // padded (+1) partial y

  // ---- register-resident weight column (fp16 pairs) ----
  int w2[NP];
  const float* colp; int cstride;
  if (g < 3) { colp = kfiz + g * HH + cg; cstride = 3 * HH; }
  else       { colp = kr + cg;            cstride = HH;     }
#pragma unroll
  for (int k = 0; k < NP; ++k) {
    f16x2 v;
    v.x = (_Float16)colp[(2 * k    ) * cstride];
    v.y = (_Float16)colp[(2 * k + 1) * cstride];
    w2[k] = __builtin_bit_cast(int, v);
  }
  const float bias = (g < 3) ? bfiz[g * HH + cg] : br[cg];

  // ---- W_out fragment (only q==0 uses it, loaded uniformly) ----
  const int o  = tid & 31;
  const int jc = tid >> 5;                 // 16 chunks of 16 h-rows
  int wo2[8];
#pragma unroll
  for (int k = 0; k < 8; ++k) {
    f16x2 v;
    v.x = (_Float16)wout[(jc * 16 + 2 * k    ) * OO + o];
    v.y = (_Float16)wout[(jc * 16 + 2 * k + 1) * OO + o];
    wo2[k] = __builtin_bit_cast(int, v);
  }
  const float bo = bout[o];

  // ---- state init ----
  float cs = x0[p * 2 * HH + HH + cg];     // c0, replicated across the 4 gate lanes
  if (tid < HH) uh[0][DD + tid] = (_Float16)x0[p * 2 * HH + tid];          // h0 (both halves)
  if (tid < DD) uh[0][tid]      = (_Float16)u[((size_t)p * TT) * DD + tid]; // u_0

  float* xown = xbuf + (size_t)((p * 2 + q      ) * 2) * 128;
  float* xpar = xbuf + (size_t)((p * 2 + (q ^ 1)) * 2) * 128;
  int*   fown = flags + (p * 2 + q      ) * 16;
  int*   fpar = flags + (p * 2 + (q ^ 1)) * 16;

  __syncthreads();

  for (int step = 0; step < TT; ++step) {
    const int cur = step & 1;
    const int nxt = cur ^ 1;

    // ---- y partial for step-1 (h_{step-1} lives in uh[cur]) ----
    if (q == 0 && step > 0) {
      const int4* hp = (const int4*)&uh[cur][DD + jc * 16];
      int4 ha = hp[0], hb = hp[1];
      float ya = 0.0f;
      ya = fdot2(b2h(wo2[0]), b2h(ha.x), ya);
      ya = fdot2(b2h(wo2[1]), b2h(ha.y), ya);
      ya = fdot2(b2h(wo2[2]), b2h(ha.z), ya);
      ya = fdot2(b2h(wo2[3]), b2h(ha.w), ya);
      ya = fdot2(b2h(wo2[4]), b2h(hb.x), ya);
      ya = fdot2(b2h(wo2[5]), b2h(hb.y), ya);
      ya = fdot2(b2h(wo2[6]), b2h(hb.z), ya);
      ya = fdot2(b2h(wo2[7]), b2h(hb.w), ya);
      yred[cur][o][jc] = ya;
    }

    // ---- P1: 320-row dot product, 4 independent fp32 chains ----
    const int4* up = (const int4*)&uh[cur][0];
    float a0 = bias, a1 = 0.0f, a2 = 0.0f, a3 = 0.0f;
#pragma unroll
    for (int k = 0; k < 40; ++k) {
      int4 hv = up[k];                       // wave-uniform broadcast read
      a0 = fdot2(b2h(w2[4 * k + 0]), b2h(hv.x), a0);
      a1 = fdot2(b2h(w2[4 * k + 1]), b2h(hv.y), a1);
      a2 = fdot2(b2h(w2[4 * k + 2]), b2h(hv.z), a2);
      a3 = fdot2(b2h(w2[4 * k + 3]), b2h(hv.w), a3);
    }
    const float pre = (a0 + a1) + (a2 + a3);

    // ---- P2: activate own gate, then swap activated values in the 4-lane group ----
    const float act = (g == 3) ? tanhf_(pre) : sigm(pre);
    const float n1 = __shfl_xor(act, 1);
    const float n2 = __shfl_xor(act, 2);
    const float n3 = __shfl_xor(act, 3);
    // value of gate G = {act,n1,n2,n3}[G ^ g]
    float f, i, z, r;
    { int m;
      m = g;     f = (m == 0) ? act : (m == 1) ? n1 : (m == 2) ? n2 : n3;
      m = g ^ 1; i = (m == 0) ? act : (m == 1) ? n1 : (m == 2) ? n2 : n3;
      m = g ^ 2; z = (m == 0) ? act : (m == 1) ? n1 : (m == 2) ? n2 : n3;
      m = g ^ 3; r = (m == 0) ? act : (m == 1) ? n1 : (m == 2) ? n2 : n3;
    }
    cs = f * cs + i * r;
    const float hn = z * tanhf_(cs);

    // ---- P3: publish own half ----
    if (g == 0) {
      uh[nxt][DD + cg] = (_Float16)hn;
      __hip_atomic_store(&xown[nxt * 128 + c], hn, __ATOMIC_RELAXED, __HIP_MEMORY_SCOPE_AGENT);
    }
    // prefetch u_{step+1} into the next parity buffer
    if (tid >= 320 && tid < 320 + DD && step + 1 < TT) {
      const int j = tid - 320;
      uh[nxt][j] = (_Float16)u[((size_t)p * TT + step + 1) * DD + j];
    }
    __syncthreads();   // B: own X stores + uh[nxt] own half + yred[cur] complete

    if (tid == 0)
      __hip_atomic_store(fown, step + 1, __ATOMIC_RELEASE, __HIP_MEMORY_SCOPE_AGENT);

    // y reduce/store for step-1 (after flag, so partner is not stalled by this)
    if (q == 0 && step > 0 && tid < OO) {
      float s = bo;
#pragma unroll
      for (int k = 0; k < 16; ++k) s += yred[cur][tid][k];
      out[((size_t)p * TT + (step - 1)) * OO + tid] = s;
    }

    // ---- P4: fetch partner half (one lane per wave spins) ----
    if (tid >= 128 && tid < 256) {
      if ((tid & 63) == 0) {
        while (__hip_atomic_load(fpar, __ATOMIC_ACQUIRE, __HIP_MEMORY_SCOPE_AGENT) < step + 1) {}
      }
      const int j = tid & 127;
      const float hv = __hip_atomic_load(&xpar[nxt * 128 + j], __ATOMIC_RELAXED, __HIP_MEMORY_SCOPE_AGENT);
      uh[nxt][DD + ((q ^ 1) << 7) + j] = (_Float16)hv;
    }
    __syncthreads();   // C: uh[nxt] fully assembled for next step
  }

  // ---- epilogue: y_{T-1} from uh[0] (T&1 == 0) ----
  if (q == 0) {
    const int4* hp = (const int4*)&uh[0][DD + jc * 16];
    int4 ha = hp[0], hb = hp[1];
    float ya = 0.0f;
    ya = fdot2(b2h(wo2[0]), b2h(ha.x), ya);
    ya = fdot2(b2h(wo2[1]), b2h(ha.y), ya);
    ya = fdot2(b2h(wo2[2]), b2h(ha.z), ya);
    ya = fdot2(b2h(wo2[3]), b2h(ha.w), ya);
    ya = fdot2(b2h(wo2[4]), b2h(hb.x), ya);
    ya = fdot2(b2h(wo2[5]), b2h(hb.y), ya);
    ya = fdot2(b2h(wo2[6]), b2h(hb.z), ya);
    ya = fdot2(b2h(wo2[7]), b2h(hb.w), ya);
    yred[0][o][jc] = ya;
    __syncthreads();
    if (tid < OO) {
      float s = bo;
#pragma unroll
      for (int k = 0; k < 16; ++k) s += yred[0][tid][k];
      out[((size_t)p * TT + (TT - 1)) * OO + tid] = s;
    }
  }
}

extern "C" void kernel_launch(void* const* d_in, const int* in_sizes, int n_in,
                              void* d_out, int out_size, void* d_ws, size_t ws_size,
                              hipStream_t stream) {
  const float* u    = (const float*)d_in[0];
  const float* x0   = (const float*)d_in[1];
  const float* kfiz = (const float*)d_in[2];
  const float* bfiz = (const float*)d_in[3];
  const float* kr   = (const float*)d_in[4];
  const float* br   = (const float*)d_in[5];
  const float* wout = (const float*)d_in[6];
  const float* bout = (const float*)d_in[7];
  float* out  = (float*)d_out;
  // ws layout: X exchange buffer [128][2][2][128] floats (256 KB), then flags
  // [128][2] ints at 64 B stride (16 KB). 0xAA poison -> flags negative -> safe.
  float* xbuf = (float*)d_ws;
  int*   flg  = (int*)((char*)d_ws + (size_t)BB * 2 * 2 * 128 * sizeof(float));
  lstm_persist<<<dim3(2 * BB), dim3(512), 0, stream>>>(
      u, x0, kfiz, bfiz, kr, br, wout, bout, out, xbuf, flg);
}